// Round 1
// baseline (103.265 us; speedup 1.0000x reference)
//
#include <hip/hip_runtime.h>

#define GAMMA 0.99f
constexpr int T_DIM = 128;
constexpr int B_DIM = 512;
constexpr int Q_DIM = 50;
constexpr int TRET  = 127;              // loss rows per b (t = 0..126)
constexpr int SLOT  = 52;               // LDS row stride (208 B, 16B-aligned)
constexpr int NPAIR = TRET * (Q_DIM/2); // 3175 (t, j-pair) slots per b
constexpr int KEEP  = -1;

// ---------------------------------------------------------------------------
// Fused kernel: one 1024-thread block per b (512 blocks = exactly 2/CU).
// Phase 1: segmented suffix scan of affine maps over t (threads 0..127,
//          Hillis-Steele, 7 rounds, DOUBLE-BUFFERED -> 1 barrier/round).
// Phase 2: stage all 127 ret rows for this b into LDS (float2 loads/stores).
// Phase 3: pair compute, TWO (t,j) columns per thread so each ret float4
//          LDS read is amortized over 2 columns (halves LDS-pipe traffic,
//          which was the phase-3 critical pipe: 13 vs 11 us).
//          5-op verified math per pair: d = ret_i - v; c = med3(d,-1,1);
//          e = d - 0.5c;  sum w*h = 0.5*sum(e*c) + (tau_j-0.5)*sum(e*|c|)
// Phase 4: per-row wave reduce -> out[t*B+b].  t=127 zero row in phase 1.
// Accumulation order per (t,j) is IDENTICAL to previous version -> bitwise
// identical output (absmax must stay 0.0).
// ---------------------------------------------------------------------------
__global__ void __launch_bounds__(1024, 8) fused_kernel(
    const float* __restrict__ reward,
    const int*   __restrict__ step_type,
    const float* __restrict__ discount,
    const float* __restrict__ value,
    const float* __restrict__ tv,
    float*       __restrict__ out) {
  __shared__ __align__(16) float sret[TRET * SLOT];   // 26.4 KB
  __shared__ __align__(16) float pacc[TRET * SLOT];   // 26.4 KB
  __shared__ float sp[2][128], sqa[2][128], sqb[2][128];
  __shared__ int   snv[2][128];
  __shared__ float s_alpha[TRET], s_beta[TRET];
  __shared__ int   s_anchor[TRET];

  const int tid = threadIdx.x;
  const int b   = blockIdx.x;

  // ---- phase 1: scan (threads 0..127 active; all threads hit barriers) ----
  float p = 1.0f, qa = 0.0f, qb = 0.0f; int nv = KEEP;
  if (tid < TRET) {
    const bool  last = (step_type[tid * B_DIM + b] == 2);
    const float d    = GAMMA * discount[(tid + 1) * B_DIM + b];
    const float r    = reward[(tid + 1) * B_DIM + b];
    p  = last ? 0.0f : d;
    qa = last ? 1.0f : 0.0f;
    qb = last ? 0.0f : r;
    nv = last ? tid  : KEEP;
  } else if (tid == TRET) {
    out[TRET * B_DIM + b] = 0.0f;       // required zero row (t = 127)
  }
  if (tid < 128) { sp[0][tid] = p; sqa[0][tid] = qa; sqb[0][tid] = qb; snv[0][tid] = nv; }
  __syncthreads();

  int cur = 0;
#pragma unroll
  for (int off = 1; off < 128; off <<= 1) {
    if (tid < 128) {
      if (tid + off < 128) {
        const float p2  = sp [cur][tid + off];
        const float qa2 = sqa[cur][tid + off];
        const float qb2 = sqb[cur][tid + off];
        const int   nv2 = snv[cur][tid + off];
        qa = fmaf(p, qa2, qa);          // self is the OUTER map
        qb = fmaf(p, qb2, qb);
        p  = p * p2;
        nv = (nv == KEEP) ? nv2 : nv;
      }
      sp [cur ^ 1][tid] = p;
      sqa[cur ^ 1][tid] = qa;
      sqb[cur ^ 1][tid] = qb;
      snv[cur ^ 1][tid] = nv;
    }
    __syncthreads();                    // one barrier per round
    cur ^= 1;
  }

  if (tid < TRET) {
    s_alpha[tid]  = p + qa;             // applied to (a=1, be=0, n=127)
    s_beta[tid]   = qb;
    s_anchor[tid] = (nv == KEEP) ? TRET : nv;
  }
  __syncthreads();

  // ---- phase 2: stage all 127 ret rows for this b (float2) ----
  for (int e = tid; e < NPAIR; e += 1024) {
    const int t = e / 25;
    const int i = (e - t * 25) * 2;
    const int n = s_anchor[t];
    const float  a  = s_alpha[t];
    const float  be = s_beta[t];
    const float2 tvv = *reinterpret_cast<const float2*>(
        &tv[(n * B_DIM + b) * Q_DIM + i]);          // 8B-aligned: (.)*200 + 8*(i/2)
    *reinterpret_cast<float2*>(&sret[t * SLOT + i]) =
        make_float2(fmaf(a, tvv.x, be), fmaf(a, tvv.y, be));
  }
  __syncthreads();

  // ---- phase 3: pair compute, 2 adjacent quantile columns per thread ----
  for (int s = tid; s < NPAIR; s += 1024) {
    const int t  = s / 25;
    const int j0 = (s - t * 25) * 2;
    const float2 vv = *reinterpret_cast<const float2*>(
        &value[(t * B_DIM + b) * Q_DIM + j0]);      // 8B-aligned, coalesced
    const float ta0 = ((float)j0 + 0.5f) * (1.0f / Q_DIM) - 0.5f;
    const float ta1 = ((float)j0 + 1.5f) * (1.0f / Q_DIM) - 0.5f;
    const float* rp = &sret[t * SLOT];

    float s1a = 0.0f, s2a = 0.0f, s1b = 0.0f, s2b = 0.0f;
    auto pair2 = [&](float reti) {
      { const float d = reti - vv.x;
        const float c = __builtin_amdgcn_fmed3f(d, -1.0f, 1.0f);
        const float e = fmaf(-0.5f, c, d);
        s1a = fmaf(e, c, s1a);          // sum huber(d)
        s2a = fmaf(e, fabsf(c), s2a); } // sum sgn(d)*huber(d)
      { const float d = reti - vv.y;
        const float c = __builtin_amdgcn_fmed3f(d, -1.0f, 1.0f);
        const float e = fmaf(-0.5f, c, d);
        s1b = fmaf(e, c, s1b);
        s2b = fmaf(e, fabsf(c), s2b); }
    };
#pragma unroll
    for (int i0 = 0; i0 < 48; i0 += 4) {
      const float4 rr = *reinterpret_cast<const float4*>(rp + i0);
      pair2(rr.x); pair2(rr.y); pair2(rr.z); pair2(rr.w);
    }
    {
      const float2 rr = *reinterpret_cast<const float2*>(rp + 48);
      pair2(rr.x); pair2(rr.y);
    }
    *reinterpret_cast<float2*>(&pacc[t * SLOT + j0]) =
        make_float2(fmaf(ta0, s2a, 0.5f * s1a), fmaf(ta1, s2b, 0.5f * s1b));
  }
  __syncthreads();

  // ---- phase 4: per-row reduce; wave w handles rows 8w..8w+7 ----
  const int w    = tid >> 6;
  const int lane = tid & 63;
#pragma unroll
  for (int k = 0; k < 8; ++k) {
    const int t = w * 8 + k;
    if (t < TRET) {
      float x = (lane < Q_DIM) ? pacc[t * SLOT + lane] : 0.0f;
#pragma unroll
      for (int off = 32; off > 0; off >>= 1)
        x += __shfl_xor(x, off, 64);
      if (lane == 0) out[t * B_DIM + b] = x * (1.0f / Q_DIM);
    }
  }
}

// ---------------------------------------------------------------------------
extern "C" void kernel_launch(void* const* d_in, const int* in_sizes, int n_in,
                              void* d_out, int out_size, void* d_ws, size_t ws_size,
                              hipStream_t stream) {
  const float* reward       = (const float*)d_in[0];
  const int*   step_type    = (const int*)  d_in[1];
  const float* discount     = (const float*)d_in[2];
  const float* value        = (const float*)d_in[3];
  const float* target_value = (const float*)d_in[4];
  float* out = (float*)d_out;

  fused_kernel<<<B_DIM, 1024, 0, stream>>>(reward, step_type, discount,
                                           value, target_value, out);
}